// Round 1
// 480.661 us; speedup vs baseline: 1.0133x; 1.0133x over previous
//
#include <hip/hip_runtime.h>
#include <math.h>

#define C_ 128
#define MID 8
#define CS 262144            // channel stride = 64*64*64 floats
#define SQRT8 2.8284271247461903f   // 2*sqrt(2)

static __device__ __forceinline__ float sigmoidf_(float z) {
    return 1.0f / (1.0f + __expf(-z));
}

// ---------------------------------------------------------------------------
// K1: gap partial sums only. grid 2048 = (b, c, g) with g = dc/4.
// Each block sums the raw corners (v.x + v.z of the even-d/even-h rows) of
// its 4-dc slab and writes one float. 64 MiB read total; rows stay L3-hot
// for K3's phase 1.
// ---------------------------------------------------------------------------
__global__ __launch_bounds__(256) void gap_partial_kernel(
    const float* __restrict__ x,
    float* __restrict__ partial)    // [2][128][8]
{
    __shared__ float red[4];
    const int blk = blockIdx.x;          // b*1024 + c*8 + g
    const int g = blk & 7;
    const int c = (blk >> 3) & 127;
    const int b = blk >> 10;
    const int tid = threadIdx.x;
    const int f = tid & 15;

    const float* xb = x + (size_t)(b * C_ + c) * CS;
    float s = 0.0f;
    #pragma unroll
    for (int k = 0; k < 8; ++k) {
        const int r   = (tid >> 4) + 16 * k;   // 0..127
        const int dcl = r >> 5;                // 0..3
        const int hc  = r & 31;
        const float4 v = ((const float4*)(
            xb + (size_t)(2 * (4 * g + dcl)) * 4096 + (size_t)(2 * hc) * 64))[f];
        s += v.x + v.z;
    }
    s += __shfl_down(s, 32);
    s += __shfl_down(s, 16);
    s += __shfl_down(s, 8);
    s += __shfl_down(s, 4);
    s += __shfl_down(s, 2);
    s += __shfl_down(s, 1);
    if ((tid & 63) == 0) red[tid >> 6] = s;
    __syncthreads();
    if (tid == 0) partial[blk] = red[0] + red[1] + red[2] + red[3];
}

// ---------------------------------------------------------------------------
// K2: one block. Reduce 8 partials per (b,c) -> gap, global MLP 128->8->128,
// fold lb2 into the gate bias: gbias[b*128+c] = gout + lb2.
// ---------------------------------------------------------------------------
__global__ __launch_bounds__(256) void gmlp_kernel(
    const float* __restrict__ partial,
    const float* __restrict__ gw1, const float* __restrict__ gb1,
    const float* __restrict__ gw2, const float* __restrict__ gb2,
    const float* __restrict__ lb2,
    float* __restrict__ gbias)      // [2][128]
{
    __shared__ float sgap[2][C_];
    __shared__ float shid[2][MID];
    const int t = threadIdx.x;
    const int b = t >> 7, c = t & 127;
    {
        const float4* p = (const float4*)(partial + (size_t)t * 8);
        const float4 a = p[0], d = p[1];
        sgap[b][c] = (a.x + a.y + a.z + a.w + d.x + d.y + d.z + d.w)
                     * (SQRT8 / 32768.0f);
    }
    __syncthreads();
    if (t < 16) {
        const int bb = t >> 3, m = t & 7;
        float a = gb1[m];
        for (int cc = 0; cc < C_; ++cc) a += gw1[m * C_ + cc] * sgap[bb][cc];
        shid[bb][m] = fmaxf(a, 0.0f);
    }
    __syncthreads();
    float a = gb2[c] + lb2[c];
    #pragma unroll
    for (int m = 0; m < MID; ++m) a += gw2[c * MID + m] * shid[b][m];
    gbias[t] = a;
}

// ---------------------------------------------------------------------------
// K3: fused local-MLP + blend. grid 4096 = (b, dc, hc, w-half); each block
// owns all 128 channels of one coarse cell (2x2x32 fine elements per ch).
// Phase 1: load the even-d/even-h row quarter (kept in registers), stage
//          x_sum corners to LDS.
// Phase 2: hidden[8][16] = relu(lw1 @ x_sum + lb1) in LDS.
// Phase 3: per channel: gate = sigmoid(gbias + lw2 @ hidden), blend
//          out = w*x + (1-w)*mean with the 3 remaining rows loaded fresh.
// x is read exactly once by this kernel; no lout buffer exists.
// ---------------------------------------------------------------------------
__global__ __launch_bounds__(256) void fused_blend_kernel(
    const float* __restrict__ x,
    const float* __restrict__ lw1, const float* __restrict__ lb1,
    const float* __restrict__ lw2,
    const float* __restrict__ gbias,
    float* __restrict__ out)
{
    __shared__ float xs[C_ * 17];     // x_sum[c][wc_local], stride 17 (banks)
    __shared__ float shid[MID * 16];  // hidden[m][wc_local]
    __shared__ float s1T[C_ * MID];   // lw1 transposed: [cc][m]
    __shared__ float s2T[MID * C_];   // lw2 transposed: [m][c]
    __shared__ float sgb[C_];

    const int blk = blockIdx.x;        // b*2048 + dc*64 + hc*2 + wh
    const int wh  = blk & 1;
    const int hc  = (blk >> 1) & 31;
    const int dc  = (blk >> 6) & 31;
    const int b   = blk >> 11;
    const int tid = threadIdx.x;
    const int f   = tid & 7;           // float4 index within 32-float half-row
    const int c0  = tid >> 3;          // 0..31

    for (int i = tid; i < MID * C_; i += 256) {
        s1T[i] = lw1[(i & 7) * C_ + (i >> 3)];      // s1T[cc*8+m] = lw1[m][cc]
        s2T[i] = lw2[(i & 127) * MID + (i >> 7)];   // s2T[m*128+c] = lw2[c][m]
    }
    if (tid < C_) sgb[tid] = gbias[b * C_ + tid];

    const float* xb = x + (size_t)b * C_ * CS
                    + (size_t)(2 * dc) * 4096 + (size_t)(2 * hc) * 64 + wh * 32;

    float4 r00[4];
    #pragma unroll
    for (int k = 0; k < 4; ++k) {
        const int c = c0 + 32 * k;
        const float4 v = ((const float4*)(xb + (size_t)c * CS))[f];
        r00[k] = v;
        xs[c * 17 + 2 * f]     = SQRT8 * v.x;
        xs[c * 17 + 2 * f + 1] = SQRT8 * v.z;
    }
    __syncthreads();

    if (tid < 128) {
        const int m = tid >> 4, wc = tid & 15;
        float a = lb1[m];
        for (int cc = 0; cc < C_; ++cc) a += s1T[cc * MID + m] * xs[cc * 17 + wc];
        shid[m * 16 + wc] = fmaxf(a, 0.0f);
    }
    __syncthreads();

    float* ob = out + (xb - x);
    #pragma unroll
    for (int k = 0; k < 4; ++k) {
        const int c = c0 + 32 * k;
        const size_t coff = (size_t)c * CS;

        const float4 a01 = ((const float4*)(xb + coff + 64))[f];
        const float4 a10 = ((const float4*)(xb + coff + 4096))[f];
        const float4 a11 = ((const float4*)(xb + coff + 4160))[f];
        const float4 a00 = r00[k];

        float d0 = sgb[c], d1 = sgb[c];
        #pragma unroll
        for (int m = 0; m < MID; ++m) {
            const float wv = s2T[m * C_ + c];
            d0 += wv * shid[m * 16 + 2 * f];
            d1 += wv * shid[m * 16 + 2 * f + 1];
        }
        const float w0 = sigmoidf_(d0);
        const float w1 = sigmoidf_(d1);

        const float mean0 = (a00.x + a00.y + a01.x + a01.y +
                             a10.x + a10.y + a11.x + a11.y) * 0.125f;
        const float mean1 = (a00.z + a00.w + a01.z + a01.w +
                             a10.z + a10.w + a11.z + a11.w) * 0.125f;
        const float om0 = (1.0f - w0) * mean0;
        const float om1 = (1.0f - w1) * mean1;

        float4 o;
        o.x = w0 * a00.x + om0; o.y = w0 * a00.y + om0;
        o.z = w1 * a00.z + om1; o.w = w1 * a00.w + om1;
        ((float4*)(ob + coff))[f] = o;
        o.x = w0 * a01.x + om0; o.y = w0 * a01.y + om0;
        o.z = w1 * a01.z + om1; o.w = w1 * a01.w + om1;
        ((float4*)(ob + coff + 64))[f] = o;
        o.x = w0 * a10.x + om0; o.y = w0 * a10.y + om0;
        o.z = w1 * a10.z + om1; o.w = w1 * a10.w + om1;
        ((float4*)(ob + coff + 4096))[f] = o;
        o.x = w0 * a11.x + om0; o.y = w0 * a11.y + om0;
        o.z = w1 * a11.z + om1; o.w = w1 * a11.w + om1;
        ((float4*)(ob + coff + 4160))[f] = o;
    }
}

extern "C" void kernel_launch(void* const* d_in, const int* in_sizes, int n_in,
                              void* d_out, int out_size, void* d_ws, size_t ws_size,
                              hipStream_t stream) {
    const float* x   = (const float*)d_in[0];
    const float* gw1 = (const float*)d_in[1];
    const float* gb1 = (const float*)d_in[2];
    const float* gw2 = (const float*)d_in[3];
    const float* gb2 = (const float*)d_in[4];
    const float* lw1 = (const float*)d_in[5];
    const float* lb1 = (const float*)d_in[6];
    const float* lw2 = (const float*)d_in[7];
    const float* lb2 = (const float*)d_in[8];
    float* o  = (float*)d_out;
    float* ws = (float*)d_ws;

    float* partial = ws;           // 2048 floats
    float* gbias   = ws + 2048;    // 256 floats

    gap_partial_kernel<<<2048, 256, 0, stream>>>(x, partial);
    gmlp_kernel<<<1, 256, 0, stream>>>(partial, gw1, gb1, gw2, gb2, lb2, gbias);
    fused_blend_kernel<<<4096, 256, 0, stream>>>(x, lw1, lb1, lw2, gbias, o);
}